// Round 15
// baseline (101.706 us; speedup 1.0000x reference)
//
#include <hip/hip_runtime.h>
#include <hip/hip_bf16.h>
#include <math.h>

typedef __attribute__((ext_vector_type(8))) short bf16x8;
typedef __attribute__((ext_vector_type(4))) short short4v;
typedef __attribute__((ext_vector_type(4))) float f32x4;
typedef __attribute__((ext_vector_type(2))) unsigned int u32x2;

#define DEVI __device__ __forceinline__

constexpr int Bb  = 2;
constexpr int Tm  = 1024;
constexpr int Ntx = 64;
constexpr int Hh  = 8;
constexpr int Ll  = 3*Tm + 5*Ntx;   // 3392
constexpr int Mm  = Bb*Ll;          // 6784
constexpr int MOT = 3*Tm;           // 3072
constexpr int UPH = 75;             // units per (b,h)
constexpr int PST = 72;             // P LDS stride (shorts)

DEVI short f2b(float f) {
  unsigned u = __builtin_bit_cast(unsigned, f);
  u = u + 0x7fffu + ((u >> 16) & 1u);
  return (short)(u >> 16);
}

DEVI void gld16(const void* g, void* l) {
  __builtin_amdgcn_global_load_lds(
      (const __attribute__((address_space(1))) unsigned*)g,
      (__attribute__((address_space(3))) unsigned*)l, 16, 0, 0);
}

DEVI f32x4 mfma16(bf16x8 a, bf16x8 b, f32x4 c) {
  return __builtin_amdgcn_mfma_f32_16x16x32_bf16(a, b, c, 0, 0, 0);
}

// ---------------- prep: cast x + LDS-tiled transpose/cast of weights ----------------

__global__ __launch_bounds__(256) void prep_kern(
    const float* __restrict__ x,  short* __restrict__ xb,
    const float* __restrict__ Wq, const float* __restrict__ Wk,
    const float* __restrict__ Wv, const float* __restrict__ Wp,
    short* __restrict__ WtQKV, short* __restrict__ WpT) {
  if (blockIdx.x < 3392) {
    int i = (blockIdx.x*256 + threadIdx.x)*4;
    float4 v = *(const float4*)(x + i);
    short4v r;
    r.x = f2b(v.x); r.y = f2b(v.y); r.z = f2b(v.z); r.w = f2b(v.w);
    *(short4v*)(xb + i) = r;
  } else {
    __shared__ float lds[64][65];
    const int t = blockIdx.x - 3392;      // 0..255
    const int mat = t >> 6;
    const int tt = t & 63;
    const int k0 = (tt >> 3)*64;
    const int n0 = (tt & 7)*64;
    const float* W = (mat == 0) ? Wq : (mat == 1) ? Wk : (mat == 2) ? Wv : Wp;
    const int lane6 = threadIdx.x & 63;
    const int row4  = threadIdx.x >> 6;
#pragma unroll
    for (int i = 0; i < 16; ++i) {
      int r = i*4 + row4;
      lds[r][lane6] = W[(size_t)(k0 + r)*512 + n0 + lane6];
    }
    __syncthreads();
    short* dst = (mat < 3) ? WtQKV + (size_t)mat*512*512 : WpT;
#pragma unroll
    for (int i = 0; i < 16; ++i) {
      int nr = i*4 + row4;
      dst[(size_t)(n0 + nr)*512 + k0 + lane6] = f2b(lds[lane6][nr]);
    }
  }
}

// ---------------- GEMM: BK=64, XOR-swizzled staging (attn-proven pattern) ----------------
// 128B tile rows; source pre-swizzled (L&127)^((row&7)<<4), read at
// (half*64+g*16)^((col&7)<<4) -> conflict-free b128 fragment reads.
// 8 k-steps instead of 16 -> half the barrier/vmcnt-drain overhead.

template<int MODE>
__global__ __launch_bounds__(256) void gemm_bt(
    const short* __restrict__ A, const short* __restrict__ Bt,
    const float* __restrict__ bias_q, const float* __restrict__ bias_k,
    const float* __restrict__ bias_v,
    short* __restrict__ Qb, short* __restrict__ Kb, short* __restrict__ Vt,
    float* __restrict__ outf) {
  __shared__ __align__(16) short At[128*64];   // 16KB
  __shared__ __align__(16) short Bs[128*64];   // 16KB
  const int tid = threadIdx.x;
  const int w = tid >> 6, lane = tid & 63;
  const int col = lane & 15, g = lane >> 4;
  const int tm = blockIdx.x, tn = blockIdx.y;
  const int wm = w >> 1, wn = w & 1;
  const int swc = (col & 7) << 4;

  f32x4 acc[4][4] = {};

  for (int k0 = 0; k0 < 512; k0 += 64) {
    __syncthreads();
#pragma unroll
    for (int it = 0; it < 4; ++it) {
      int L = it*4096 + tid*16;          // byte offset within 16KB tile
      int row = L >> 7;
      int cb = (L & 127) ^ ((row & 7) << 4);
      gld16((const char*)A  + ((size_t)(tm*128 + row))*1024 + k0*2 + cb,
            (char*)At + it*4096 + w*1024);
      gld16((const char*)Bt + ((size_t)(tn*128 + row))*1024 + k0*2 + cb,
            (char*)Bs + it*4096 + w*1024);
    }
    __syncthreads();
#pragma unroll
    for (int half = 0; half < 2; ++half) {
      bf16x8 af[4], bfr[4];
#pragma unroll
      for (int i = 0; i < 4; ++i) {
        int row = wm*64 + i*16 + col;
        af[i] = *(const bf16x8*)((const char*)At + row*128 + ((half*64 + g*16) ^ swc));
      }
#pragma unroll
      for (int jj = 0; jj < 4; ++jj) {
        int row = wn*64 + jj*16 + col;
        bfr[jj] = *(const bf16x8*)((const char*)Bs + row*128 + ((half*64 + g*16) ^ swc));
      }
#pragma unroll
      for (int i = 0; i < 4; ++i)
#pragma unroll
        for (int jj = 0; jj < 4; ++jj)
          acc[i][jj] = mfma16(af[i], bfr[jj], acc[i][jj]);
    }
  }

#pragma unroll
  for (int i = 0; i < 4; ++i) {
    int mbase = tm*128 + wm*64 + i*16 + g*4;
#pragma unroll
    for (int j = 0; j < 4; ++j) {
      int ncol = tn*128 + wn*64 + j*16 + col;
#pragma unroll
      for (int r = 0; r < 4; ++r) {
        int mrow = mbase + r;
        float v = acc[i][j][r];
        if constexpr (MODE == 0) {
          float bias = (ncol < 512) ? bias_q[ncol]
                     : (ncol < 1024) ? bias_k[ncol - 512] : bias_v[ncol - 1024];
          v += bias;
          int bb = (mrow >= Ll) ? 1 : 0;
          int lpos = mrow - bb*Ll;
          int nn = ncol & 511;
          int h = nn >> 6, dd = nn & 63;
          int bh = bb*8 + h;
          if (ncol < 512) {
            // fold softmax scale (1/sqrt(64))*log2(e) into Q
            Qb[((size_t)(bh*Ll + lpos))*64 + dd] = f2b(v*0.18033688f);
          } else if (ncol < 1024) {
            Kb[((size_t)(bh*Ll + lpos))*64 + dd] = f2b(v);
          } else {
            Vt[((size_t)(bh*64 + dd))*Ll + lpos] = f2b(v);
          }
        } else {
          outf[(size_t)mrow*512 + ncol] = v + bias_q[ncol];
        }
      }
    }
  }
}

// ---------------- attention: r12/r14 structure verbatim (known-good) ----------------
// NOTE (r13 lesson): no agent-scope fence/atomic fusion here — per-XCD L2s are
// non-coherent; fences force L2 writebacks that evict K/V (5x regression).

__global__ __launch_bounds__(256) void attn_kern(
    const short* __restrict__ Qb, const short* __restrict__ Kb,
    const short* __restrict__ Vt, float* __restrict__ slots,
    short* __restrict__ attout) {
  __shared__ __align__(16) short Kls[2][4096];
  __shared__ __align__(16) short Vls[2][4096];
  __shared__ __align__(16) short Pls[4][32*PST];
  const int tid = threadIdx.x;
  const int w = tid >> 6, lane = tid & 63;
  const int col = lane & 15, g = lane >> 4;

  const int v  = (blockIdx.x & 7)*150 + (blockIdx.x >> 3);  // 1200 = 8*150
  const int bh = v / UPH;
  const int lr = v - bh*UPH;

  int qsec, seg = 0, j = 0, t3 = 0;
  if (lr < 56) {
    int jj = lr/7, s = lr - jj*7;
    j = 7 - jj;
    if (s == 0)      qsec = 0;
    else if (s <= 3) { qsec = 1; seg = s - 1; }
    else             { qsec = 2; seg = s - 4; }
  } else if (lr < 72) {
    int t = lr - 56; qsec = 1 + (t & 1); j = t >> 1; seg = 3;
  } else { qsec = 3; t3 = lr - 72; }

  const int q0b = (qsec < 3) ? qsec*Tm + j*128 : MOT + ((t3 == 2) ? 192 : t3*128);
  const int t0w = j*128 + w*32;         // section-local first row of this wave
  const int q0w = q0b + w*32;

  int kbase = 0, off = 0, nb;
  bool masked;
  if (qsec == 3)      { kbase = MOT;  nb = 5;       masked = false; }
  else if (qsec == 0) { kbase = 0;    nb = 2*j + 2; masked = true; off = 0; }
  else if (seg == 0)  { kbase = 0;    nb = 2*j + 2; masked = true; off = 0; }
  else if (seg == 1)  { kbase = Tm;   nb = 2*j + 2; masked = true; off = (qsec == 1) ? 1 : 0; }
  else if (seg == 2)  { kbase = 2*Tm; nb = 2*j + 2; masked = true; off = 1; }
  else                { kbase = 0;    nb = 4;       masked = false; }  // seg3: text domains

  auto keyof = [&](int i) -> int {
    if (qsec == 3) return MOT + i*64;
    if (!masked) { int d = (i == 0) ? ((qsec == 1) ? 0 : 1) : i + 1; return MOT + d*64; }
    return kbase + i*64;
  };

  const short* Kbase_ = Kb + (size_t)bh*Ll*64;
  const short* Vbase_ = Vt + (size_t)bh*64*Ll;

  bf16x8 aq[2][2];
#pragma unroll
  for (int qf = 0; qf < 2; ++qf) {
    const short* p = Qb + ((size_t)bh*Ll + q0w + qf*16 + col)*64;
    aq[qf][0] = *(const bf16x8*)(p + g*8);
    aq[qf][1] = *(const bf16x8*)(p + 32 + g*8);
  }
  const int qv[2] = { t0w + col, t0w + 16 + col };  // per-lane q (section-local)

  float ls[2] = {0.f, 0.f};
  f32x4 out[2][4] = {};

  auto stage = [&](int buf, int key0) {
#pragma unroll
    for (int it = 0; it < 2; ++it) {
      int L = it*4096 + tid*16;
      int row = L >> 7;
      int sw = (row & 7) << 4;
      gld16((const char*)Kbase_ + (size_t)key0*128 + (L ^ sw),
            (char*)&Kls[buf][0] + it*4096 + w*1024);
      gld16((const char*)(Vbase_ + (size_t)row*Ll + key0) + ((L & 127) ^ sw),
            (char*)&Vls[buf][0] + it*4096 + w*1024);
    }
  };

  auto compute = [&](int buf, int i) {
    const int swc = (col & 7) << 4;
    f32x4 s[2][4];
    __builtin_amdgcn_s_setprio(1);
#pragma unroll
    for (int kk = 0; kk < 4; ++kk) {
      const char* base = (const char*)&Kls[buf][0] + (kk*16 + col)*128;
      bf16x8 k0 = *(const bf16x8*)(base + ((g*16) ^ swc));
      bf16x8 k1 = *(const bf16x8*)(base + ((64 + g*16) ^ swc));
#pragma unroll
      for (int qf = 0; qf < 2; ++qf) {
        f32x4 t = {0,0,0,0};
        t = mfma16(k0, aq[qf][0], t);   // swapped: S^T[key=g*4+r][q=col]
        t = mfma16(k1, aq[qf][1], t);
        s[qf][kk] = t;
      }
    }
    __builtin_amdgcn_s_setprio(0);
    const bool dm = masked && (i*64 + 63 + off > t0w);
    const int kl = i*64 + off + g*4;
    short* pw = &Pls[w][0];
#pragma unroll
    for (int qf = 0; qf < 2; ++qf) {
      float lsl = 0.f;
#pragma unroll
      for (int kk = 0; kk < 4; ++kk) {
        float pe[4];
#pragma unroll
        for (int r = 0; r < 4; ++r) {
          float p = __builtin_amdgcn_exp2f(s[qf][kk][r]);
          if (dm && (kl + kk*16 + r > qv[qf])) p = 0.f;
          pe[r] = p; lsl += p;
        }
        unsigned pk0, pk1;
        asm("v_cvt_pk_bf16_f32 %0, %1, %2" : "=v"(pk0) : "v"(pe[0]), "v"(pe[1]));
        asm("v_cvt_pk_bf16_f32 %0, %1, %2" : "=v"(pk1) : "v"(pe[2]), "v"(pe[3]));
        u32x2 pk; pk.x = pk0; pk.y = pk1;
        *(u32x2*)(pw + (qf*16 + col)*PST + kk*16 + g*4) = pk;   // 4 keys, b64
      }
      ls[qf] += lsl;
    }
    bf16x8 pa[2][2];
#pragma unroll
    for (int qf = 0; qf < 2; ++qf) {
      const short* base2 = &Pls[w][0] + (qf*16 + col)*PST;
      pa[qf][0] = *(const bf16x8*)(base2 + g*8);
      pa[qf][1] = *(const bf16x8*)(base2 + 32 + g*8);
    }
    __builtin_amdgcn_s_setprio(1);
#pragma unroll
    for (int ch = 0; ch < 4; ++ch) {
      const char* base = (const char*)&Vls[buf][0] + (ch*16 + col)*128;
      bf16x8 v0 = *(const bf16x8*)(base + ((g*16) ^ swc));
      bf16x8 v1 = *(const bf16x8*)(base + ((64 + g*16) ^ swc));
#pragma unroll
      for (int qf = 0; qf < 2; ++qf) {
        out[qf][ch] = mfma16(pa[qf][0], v0, out[qf][ch]);
        out[qf][ch] = mfma16(pa[qf][1], v1, out[qf][ch]);
      }
    }
    __builtin_amdgcn_s_setprio(0);
  };

  stage(0, keyof(0));
  for (int i = 0; i < nb; ++i) {
    if (i + 1 < nb) {
      stage((i + 1) & 1, keyof(i + 1));
      asm volatile("s_waitcnt vmcnt(4)" ::: "memory");   // tile i landed; next 4 in flight
    } else {
      asm volatile("s_waitcnt vmcnt(0)" ::: "memory");
    }
    __builtin_amdgcn_sched_barrier(0);
    __builtin_amdgcn_s_barrier();
    bool skip = masked && (t0w + 31 < i*64 + off);       // wave fully masked
    if (!skip) compute(i & 1, i);
    __builtin_amdgcn_s_barrier();                        // protect buf reuse
  }

  float rs[2];
#pragma unroll
  for (int qf = 0; qf < 2; ++qf) {
    float t = ls[qf];
    t += __shfl_xor(t, 16);
    t += __shfl_xor(t, 32);
    rs[qf] = t;                         // row-sum for q = col (section-local)
  }

  if (qsec == 1 || qsec == 2) {
    float* sp = slots + ((((size_t)bh*2 + (qsec - 1))*8 + j)*4 + seg)*8320;
#pragma unroll
    for (int qf = 0; qf < 2; ++qf) {
#pragma unroll
      for (int ch = 0; ch < 4; ++ch)
#pragma unroll
        for (int r = 0; r < 4; ++r)
          sp[(w*32 + qf*16 + g*4 + r)*64 + ch*16 + col] = out[qf][ch][r];
      if (g == 0)
        sp[8192 + w*32 + qf*16 + col] = rs[qf];
    }
  } else {
    const int b = bh >> 3, h = bh & 7;
#pragma unroll
    for (int qf = 0; qf < 2; ++qf)
#pragma unroll
      for (int r = 0; r < 4; ++r) {
        float dv = __shfl(rs[qf], g*4 + r);   // gather row-indexed sum
        float inv = 1.0f / dv;
        size_t rowoff = ((size_t)(b*Ll + q0w + qf*16 + g*4 + r))*512 + h*64;
#pragma unroll
        for (int ch = 0; ch < 4; ++ch)
          attout[rowoff + ch*16 + col] = f2b(out[qf][ch][r]*inv);
      }
  }
}

// finalize: sum 4 seg-slots per sec1/2 row, normalize, write att
__global__ __launch_bounds__(256) void fin_kern(const float* __restrict__ slots,
                                                short* __restrict__ attout) {
  const int w = threadIdx.x >> 6, lane = threadIdx.x & 63;
  const int ridx = blockIdx.x*4 + w;       // 0..32767
  const int bh = ridx >> 11;
  const int rr = ridx & 2047;
  const int qsec = 1 + (rr >> 10);
  const int rl = rr & 1023;
  const int j = rl >> 7;
  const int row_local = rl & 127;
  const float* base = slots + (((size_t)bh*2 + (qsec - 1))*8 + j)*4*8320;
  float a = 0.f, l = 0.f;
#pragma unroll
  for (int s = 0; s < 4; ++s) {
    a += base[s*8320 + row_local*64 + lane];
    l += base[s*8320 + 8192 + row_local];
  }
  const int b = bh >> 3, h = bh & 7;
  attout[((size_t)(b*Ll + qsec*Tm + rl))*512 + h*64 + lane] = f2b(a / l);
}

// ---------------- launch ----------------

extern "C" void kernel_launch(void* const* d_in, const int* in_sizes, int n_in,
                              void* d_out, int out_size, void* d_ws, size_t ws_size,
                              hipStream_t stream) {
  const float* x  = (const float*)d_in[0];
  const float* Wq = (const float*)d_in[1];
  const float* bq = (const float*)d_in[2];
  const float* Wk = (const float*)d_in[3];
  const float* bk = (const float*)d_in[4];
  const float* Wv = (const float*)d_in[5];
  const float* bv = (const float*)d_in[6];
  const float* Wp = (const float*)d_in[7];
  const float* bp = (const float*)d_in[8];
  float* out = (float*)d_out;

  short* ws = (short*)d_ws;
  constexpr size_t SZ  = (size_t)Mm*512;
  short* xb    = ws;
  short* WtQKV = xb + SZ;
  short* WpT   = WtQKV + (size_t)1536*512;
  short* Qb    = WpT + (size_t)512*512;
  short* Kb    = Qb + SZ;
  short* Vt    = Kb + SZ;
  short* att   = Vt + SZ;
  float* slots = (float*)(att + SZ);   // 16*2*8*4 slots x 8320 f32 = 34 MB

  prep_kern<<<dim3(3392 + 256), dim3(256), 0, stream>>>(x, xb, Wq, Wk, Wv, Wp,
                                                        WtQKV, WpT);
  gemm_bt<0><<<dim3(53, 12), dim3(256), 0, stream>>>(xb, WtQKV, bq, bk, bv,
                                                     Qb, Kb, Vt, nullptr);
  attn_kern<<<dim3(1200), dim3(256), 0, stream>>>(Qb, Kb, Vt, slots, att);
  fin_kern<<<dim3(8192), dim3(256), 0, stream>>>(slots, att);
  gemm_bt<1><<<dim3(53, 4), dim3(256), 0, stream>>>(att, WpT, bp, nullptr, nullptr,
                                                    nullptr, nullptr, nullptr, out);
}

// Round 16
// 94.607 us; speedup vs baseline: 1.0750x; 1.0750x over previous
//
#include <hip/hip_runtime.h>
#include <hip/hip_bf16.h>
#include <math.h>

typedef __attribute__((ext_vector_type(8))) short bf16x8;
typedef __attribute__((ext_vector_type(4))) short short4v;
typedef __attribute__((ext_vector_type(4))) float f32x4;
typedef __attribute__((ext_vector_type(2))) unsigned int u32x2;

#define DEVI __device__ __forceinline__

constexpr int Bb  = 2;
constexpr int Tm  = 1024;
constexpr int Ntx = 64;
constexpr int Hh  = 8;
constexpr int Ll  = 3*Tm + 5*Ntx;   // 3392
constexpr int Mm  = Bb*Ll;          // 6784
constexpr int MOT = 3*Tm;           // 3072
constexpr int UPH = 75;             // units per (b,h)
constexpr int PST = 72;             // P LDS stride (shorts)

DEVI short f2b(float f) {
  unsigned u = __builtin_bit_cast(unsigned, f);
  u = u + 0x7fffu + ((u >> 16) & 1u);
  return (short)(u >> 16);
}

DEVI void gld16(const void* g, void* l) {
  __builtin_amdgcn_global_load_lds(
      (const __attribute__((address_space(1))) unsigned*)g,
      (__attribute__((address_space(3))) unsigned*)l, 16, 0, 0);
}

DEVI f32x4 mfma16(bf16x8 a, bf16x8 b, f32x4 c) {
  return __builtin_amdgcn_mfma_f32_16x16x32_bf16(a, b, c, 0, 0, 0);
}

// ---------------- prep: cast x + LDS-tiled transpose/cast of weights ----------------

__global__ __launch_bounds__(256) void prep_kern(
    const float* __restrict__ x,  short* __restrict__ xb,
    const float* __restrict__ Wq, const float* __restrict__ Wk,
    const float* __restrict__ Wv, const float* __restrict__ Wp,
    short* __restrict__ WtQKV, short* __restrict__ WpT) {
  if (blockIdx.x < 3392) {
    int i = (blockIdx.x*256 + threadIdx.x)*4;
    float4 v = *(const float4*)(x + i);
    short4v r;
    r.x = f2b(v.x); r.y = f2b(v.y); r.z = f2b(v.z); r.w = f2b(v.w);
    *(short4v*)(xb + i) = r;
  } else {
    __shared__ float lds[64][65];
    const int t = blockIdx.x - 3392;      // 0..255
    const int mat = t >> 6;
    const int tt = t & 63;
    const int k0 = (tt >> 3)*64;
    const int n0 = (tt & 7)*64;
    const float* W = (mat == 0) ? Wq : (mat == 1) ? Wk : (mat == 2) ? Wv : Wp;
    const int lane6 = threadIdx.x & 63;
    const int row4  = threadIdx.x >> 6;
#pragma unroll
    for (int i = 0; i < 16; ++i) {
      int r = i*4 + row4;
      lds[r][lane6] = W[(size_t)(k0 + r)*512 + n0 + lane6];
    }
    __syncthreads();
    short* dst = (mat < 3) ? WtQKV + (size_t)mat*512*512 : WpT;
#pragma unroll
    for (int i = 0; i < 16; ++i) {
      int nr = i*4 + row4;
      dst[(size_t)(n0 + nr)*512 + k0 + lane6] = f2b(lds[lane6][nr]);
    }
  }
}

// ---------------- GEMM (r14 verbatim: BK=32, known-good) ----------------
// NOTE (r15 lesson): BK=64 + XOR-swizzled staging regressed (~2x on the GEMM
// dispatches) — do not revisit without per-dispatch counter evidence.

template<int MODE>
__global__ __launch_bounds__(256) void gemm_bt(
    const short* __restrict__ A, const short* __restrict__ Bt,
    const float* __restrict__ bias_q, const float* __restrict__ bias_k,
    const float* __restrict__ bias_v,
    short* __restrict__ Qb, short* __restrict__ Kb, short* __restrict__ Vt,
    float* __restrict__ outf) {
  __shared__ __align__(16) short At[128*32];
  __shared__ __align__(16) short Bs[128*32];
  const int tid = threadIdx.x;
  const int w = tid >> 6, lane = tid & 63;
  const int col = lane & 15, g = lane >> 4;
  const int tm = blockIdx.x, tn = blockIdx.y;
  const int wm = w >> 1, wn = w & 1;

  f32x4 acc[4][4] = {};

  for (int k0 = 0; k0 < 512; k0 += 32) {
    __syncthreads();
#pragma unroll
    for (int it = 0; it < 2; ++it) {
      int e0 = w*512 + it*2048 + lane*8;
      int row = e0 >> 5, cc = e0 & 31;
      gld16(A  + (size_t)(tm*128 + row)*512 + k0 + cc, At + w*512 + it*2048);
      gld16(Bt + (size_t)(tn*128 + row)*512 + k0 + cc, Bs + w*512 + it*2048);
    }
    __syncthreads();
    bf16x8 af[4], bfr[4];
#pragma unroll
    for (int i = 0; i < 4; ++i)
      af[i] = *(const bf16x8*)(At + (wm*64 + i*16 + col)*32 + g*8);
#pragma unroll
    for (int j = 0; j < 4; ++j)
      bfr[j] = *(const bf16x8*)(Bs + (wn*64 + j*16 + col)*32 + g*8);
#pragma unroll
    for (int i = 0; i < 4; ++i)
#pragma unroll
      for (int j = 0; j < 4; ++j)
        acc[i][j] = mfma16(af[i], bfr[j], acc[i][j]);
  }

#pragma unroll
  for (int i = 0; i < 4; ++i) {
    int mbase = tm*128 + wm*64 + i*16 + g*4;
#pragma unroll
    for (int j = 0; j < 4; ++j) {
      int ncol = tn*128 + wn*64 + j*16 + col;
#pragma unroll
      for (int r = 0; r < 4; ++r) {
        int mrow = mbase + r;
        float v = acc[i][j][r];
        if constexpr (MODE == 0) {
          float bias = (ncol < 512) ? bias_q[ncol]
                     : (ncol < 1024) ? bias_k[ncol - 512] : bias_v[ncol - 1024];
          v += bias;
          int bb = (mrow >= Ll) ? 1 : 0;
          int lpos = mrow - bb*Ll;
          int nn = ncol & 511;
          int h = nn >> 6, dd = nn & 63;
          int bh = bb*8 + h;
          if (ncol < 512) {
            // fold softmax scale (1/sqrt(64))*log2(e) into Q
            Qb[((size_t)(bh*Ll + lpos))*64 + dd] = f2b(v*0.18033688f);
          } else if (ncol < 1024) {
            Kb[((size_t)(bh*Ll + lpos))*64 + dd] = f2b(v);
          } else {
            Vt[((size_t)(bh*64 + dd))*Ll + lpos] = f2b(v);
          }
        } else {
          outf[(size_t)mrow*512 + ncol] = v + bias_q[ncol];
        }
      }
    }
  }
}

// ---------------- attention: r12/r14 structure verbatim (known-good) ----------------
// NOTE (r13 lesson): no agent-scope fence/atomic fusion here — per-XCD L2s are
// non-coherent; fences force L2 writebacks that evict K/V (5x regression).

__global__ __launch_bounds__(256) void attn_kern(
    const short* __restrict__ Qb, const short* __restrict__ Kb,
    const short* __restrict__ Vt, float* __restrict__ slots,
    short* __restrict__ attout) {
  __shared__ __align__(16) short Kls[2][4096];
  __shared__ __align__(16) short Vls[2][4096];
  __shared__ __align__(16) short Pls[4][32*PST];
  const int tid = threadIdx.x;
  const int w = tid >> 6, lane = tid & 63;
  const int col = lane & 15, g = lane >> 4;

  const int v  = (blockIdx.x & 7)*150 + (blockIdx.x >> 3);  // 1200 = 8*150
  const int bh = v / UPH;
  const int lr = v - bh*UPH;

  int qsec, seg = 0, j = 0, t3 = 0;
  if (lr < 56) {
    int jj = lr/7, s = lr - jj*7;
    j = 7 - jj;
    if (s == 0)      qsec = 0;
    else if (s <= 3) { qsec = 1; seg = s - 1; }
    else             { qsec = 2; seg = s - 4; }
  } else if (lr < 72) {
    int t = lr - 56; qsec = 1 + (t & 1); j = t >> 1; seg = 3;
  } else { qsec = 3; t3 = lr - 72; }

  const int q0b = (qsec < 3) ? qsec*Tm + j*128 : MOT + ((t3 == 2) ? 192 : t3*128);
  const int t0w = j*128 + w*32;         // section-local first row of this wave
  const int q0w = q0b + w*32;

  int kbase = 0, off = 0, nb;
  bool masked;
  if (qsec == 3)      { kbase = MOT;  nb = 5;       masked = false; }
  else if (qsec == 0) { kbase = 0;    nb = 2*j + 2; masked = true; off = 0; }
  else if (seg == 0)  { kbase = 0;    nb = 2*j + 2; masked = true; off = 0; }
  else if (seg == 1)  { kbase = Tm;   nb = 2*j + 2; masked = true; off = (qsec == 1) ? 1 : 0; }
  else if (seg == 2)  { kbase = 2*Tm; nb = 2*j + 2; masked = true; off = 1; }
  else                { kbase = 0;    nb = 4;       masked = false; }  // seg3: text domains

  auto keyof = [&](int i) -> int {
    if (qsec == 3) return MOT + i*64;
    if (!masked) { int d = (i == 0) ? ((qsec == 1) ? 0 : 1) : i + 1; return MOT + d*64; }
    return kbase + i*64;
  };

  const short* Kbase_ = Kb + (size_t)bh*Ll*64;
  const short* Vbase_ = Vt + (size_t)bh*64*Ll;

  bf16x8 aq[2][2];
#pragma unroll
  for (int qf = 0; qf < 2; ++qf) {
    const short* p = Qb + ((size_t)bh*Ll + q0w + qf*16 + col)*64;
    aq[qf][0] = *(const bf16x8*)(p + g*8);
    aq[qf][1] = *(const bf16x8*)(p + 32 + g*8);
  }
  const int qv[2] = { t0w + col, t0w + 16 + col };  // per-lane q (section-local)

  float ls[2] = {0.f, 0.f};
  f32x4 out[2][4] = {};

  auto stage = [&](int buf, int key0) {
#pragma unroll
    for (int it = 0; it < 2; ++it) {
      int L = it*4096 + tid*16;
      int row = L >> 7;
      int sw = (row & 7) << 4;
      gld16((const char*)Kbase_ + (size_t)key0*128 + (L ^ sw),
            (char*)&Kls[buf][0] + it*4096 + w*1024);
      gld16((const char*)(Vbase_ + (size_t)row*Ll + key0) + ((L & 127) ^ sw),
            (char*)&Vls[buf][0] + it*4096 + w*1024);
    }
  };

  auto compute = [&](int buf, int i) {
    const int swc = (col & 7) << 4;
    f32x4 s[2][4];
    __builtin_amdgcn_s_setprio(1);
#pragma unroll
    for (int kk = 0; kk < 4; ++kk) {
      const char* base = (const char*)&Kls[buf][0] + (kk*16 + col)*128;
      bf16x8 k0 = *(const bf16x8*)(base + ((g*16) ^ swc));
      bf16x8 k1 = *(const bf16x8*)(base + ((64 + g*16) ^ swc));
#pragma unroll
      for (int qf = 0; qf < 2; ++qf) {
        f32x4 t = {0,0,0,0};
        t = mfma16(k0, aq[qf][0], t);   // swapped: S^T[key=g*4+r][q=col]
        t = mfma16(k1, aq[qf][1], t);
        s[qf][kk] = t;
      }
    }
    __builtin_amdgcn_s_setprio(0);
    const bool dm = masked && (i*64 + 63 + off > t0w);
    const int kl = i*64 + off + g*4;
    short* pw = &Pls[w][0];
#pragma unroll
    for (int qf = 0; qf < 2; ++qf) {
      float lsl = 0.f;
#pragma unroll
      for (int kk = 0; kk < 4; ++kk) {
        float pe[4];
#pragma unroll
        for (int r = 0; r < 4; ++r) {
          float p = __builtin_amdgcn_exp2f(s[qf][kk][r]);
          if (dm && (kl + kk*16 + r > qv[qf])) p = 0.f;
          pe[r] = p; lsl += p;
        }
        unsigned pk0, pk1;
        asm("v_cvt_pk_bf16_f32 %0, %1, %2" : "=v"(pk0) : "v"(pe[0]), "v"(pe[1]));
        asm("v_cvt_pk_bf16_f32 %0, %1, %2" : "=v"(pk1) : "v"(pe[2]), "v"(pe[3]));
        u32x2 pk; pk.x = pk0; pk.y = pk1;
        *(u32x2*)(pw + (qf*16 + col)*PST + kk*16 + g*4) = pk;   // 4 keys, b64
      }
      ls[qf] += lsl;
    }
    bf16x8 pa[2][2];
#pragma unroll
    for (int qf = 0; qf < 2; ++qf) {
      const short* base2 = &Pls[w][0] + (qf*16 + col)*PST;
      pa[qf][0] = *(const bf16x8*)(base2 + g*8);
      pa[qf][1] = *(const bf16x8*)(base2 + 32 + g*8);
    }
    __builtin_amdgcn_s_setprio(1);
#pragma unroll
    for (int ch = 0; ch < 4; ++ch) {
      const char* base = (const char*)&Vls[buf][0] + (ch*16 + col)*128;
      bf16x8 v0 = *(const bf16x8*)(base + ((g*16) ^ swc));
      bf16x8 v1 = *(const bf16x8*)(base + ((64 + g*16) ^ swc));
#pragma unroll
      for (int qf = 0; qf < 2; ++qf) {
        out[qf][ch] = mfma16(pa[qf][0], v0, out[qf][ch]);
        out[qf][ch] = mfma16(pa[qf][1], v1, out[qf][ch]);
      }
    }
    __builtin_amdgcn_s_setprio(0);
  };

  stage(0, keyof(0));
  for (int i = 0; i < nb; ++i) {
    if (i + 1 < nb) {
      stage((i + 1) & 1, keyof(i + 1));
      asm volatile("s_waitcnt vmcnt(4)" ::: "memory");   // tile i landed; next 4 in flight
    } else {
      asm volatile("s_waitcnt vmcnt(0)" ::: "memory");
    }
    __builtin_amdgcn_sched_barrier(0);
    __builtin_amdgcn_s_barrier();
    bool skip = masked && (t0w + 31 < i*64 + off);       // wave fully masked
    if (!skip) compute(i & 1, i);
    __builtin_amdgcn_s_barrier();                        // protect buf reuse
  }

  float rs[2];
#pragma unroll
  for (int qf = 0; qf < 2; ++qf) {
    float t = ls[qf];
    t += __shfl_xor(t, 16);
    t += __shfl_xor(t, 32);
    rs[qf] = t;                         // row-sum for q = col (section-local)
  }

  if (qsec == 1 || qsec == 2) {
    float* sp = slots + ((((size_t)bh*2 + (qsec - 1))*8 + j)*4 + seg)*8320;
#pragma unroll
    for (int qf = 0; qf < 2; ++qf) {
#pragma unroll
      for (int ch = 0; ch < 4; ++ch)
#pragma unroll
        for (int r = 0; r < 4; ++r)
          sp[(w*32 + qf*16 + g*4 + r)*64 + ch*16 + col] = out[qf][ch][r];
      if (g == 0)
        sp[8192 + w*32 + qf*16 + col] = rs[qf];
    }
  } else {
    const int b = bh >> 3, h = bh & 7;
#pragma unroll
    for (int qf = 0; qf < 2; ++qf)
#pragma unroll
      for (int r = 0; r < 4; ++r) {
        float dv = __shfl(rs[qf], g*4 + r);   // gather row-indexed sum
        float inv = 1.0f / dv;
        size_t rowoff = ((size_t)(b*Ll + q0w + qf*16 + g*4 + r))*512 + h*64;
#pragma unroll
        for (int ch = 0; ch < 4; ++ch)
          attout[rowoff + ch*16 + col] = f2b(out[qf][ch][r]*inv);
      }
  }
}

// finalize: sum 4 seg-slots per sec1/2 row, normalize, write att
__global__ __launch_bounds__(256) void fin_kern(const float* __restrict__ slots,
                                                short* __restrict__ attout) {
  const int w = threadIdx.x >> 6, lane = threadIdx.x & 63;
  const int ridx = blockIdx.x*4 + w;       // 0..32767
  const int bh = ridx >> 11;
  const int rr = ridx & 2047;
  const int qsec = 1 + (rr >> 10);
  const int rl = rr & 1023;
  const int j = rl >> 7;
  const int row_local = rl & 127;
  const float* base = slots + (((size_t)bh*2 + (qsec - 1))*8 + j)*4*8320;
  float a = 0.f, l = 0.f;
#pragma unroll
  for (int s = 0; s < 4; ++s) {
    a += base[s*8320 + row_local*64 + lane];
    l += base[s*8320 + 8192 + row_local];
  }
  const int b = bh >> 3, h = bh & 7;
  attout[((size_t)(b*Ll + qsec*Tm + rl))*512 + h*64 + lane] = f2b(a / l);
}

// ---------------- launch ----------------

extern "C" void kernel_launch(void* const* d_in, const int* in_sizes, int n_in,
                              void* d_out, int out_size, void* d_ws, size_t ws_size,
                              hipStream_t stream) {
  const float* x  = (const float*)d_in[0];
  const float* Wq = (const float*)d_in[1];
  const float* bq = (const float*)d_in[2];
  const float* Wk = (const float*)d_in[3];
  const float* bk = (const float*)d_in[4];
  const float* Wv = (const float*)d_in[5];
  const float* bv = (const float*)d_in[6];
  const float* Wp = (const float*)d_in[7];
  const float* bp = (const float*)d_in[8];
  float* out = (float*)d_out;

  short* ws = (short*)d_ws;
  constexpr size_t SZ  = (size_t)Mm*512;
  short* xb    = ws;
  short* WtQKV = xb + SZ;
  short* WpT   = WtQKV + (size_t)1536*512;
  short* Qb    = WpT + (size_t)512*512;
  short* Kb    = Qb + SZ;
  short* Vt    = Kb + SZ;
  short* att   = Vt + SZ;
  float* slots = (float*)(att + SZ);   // 16*2*8*4 slots x 8320 f32 = 34 MB

  prep_kern<<<dim3(3392 + 256), dim3(256), 0, stream>>>(x, xb, Wq, Wk, Wv, Wp,
                                                        WtQKV, WpT);
  gemm_bt<0><<<dim3(53, 12), dim3(256), 0, stream>>>(xb, WtQKV, bq, bk, bv,
                                                     Qb, Kb, Vt, nullptr);
  attn_kern<<<dim3(1200), dim3(256), 0, stream>>>(Qb, Kb, Vt, slots, att);
  fin_kern<<<dim3(8192), dim3(256), 0, stream>>>(slots, att);
  gemm_bt<1><<<dim3(53, 4), dim3(256), 0, stream>>>(att, WpT, bp, nullptr, nullptr,
                                                    nullptr, nullptr, nullptr, out);
}

// Round 17
// 91.142 us; speedup vs baseline: 1.1159x; 1.0380x over previous
//
#include <hip/hip_runtime.h>
#include <hip/hip_bf16.h>
#include <math.h>

typedef __attribute__((ext_vector_type(8))) short bf16x8;
typedef __attribute__((ext_vector_type(4))) short short4v;
typedef __attribute__((ext_vector_type(4))) float f32x4;
typedef __attribute__((ext_vector_type(2))) unsigned int u32x2;

#define DEVI __device__ __forceinline__

constexpr int Bb  = 2;
constexpr int Tm  = 1024;
constexpr int Ntx = 64;
constexpr int Hh  = 8;
constexpr int Ll  = 3*Tm + 5*Ntx;   // 3392
constexpr int Mm  = Bb*Ll;          // 6784
constexpr int MOT = 3*Tm;           // 3072
constexpr int UPH = 75;             // units per (b,h)
constexpr int PST = 72;             // P LDS stride (shorts)

DEVI short f2b(float f) {
  unsigned u = __builtin_bit_cast(unsigned, f);
  u = u + 0x7fffu + ((u >> 16) & 1u);
  return (short)(u >> 16);
}

DEVI float b2f(short s) {
  unsigned u = ((unsigned)(unsigned short)s) << 16;
  return __builtin_bit_cast(float, u);
}

DEVI void gld16(const void* g, void* l) {
  __builtin_amdgcn_global_load_lds(
      (const __attribute__((address_space(1))) unsigned*)g,
      (__attribute__((address_space(3))) unsigned*)l, 16, 0, 0);
}

DEVI f32x4 mfma16(bf16x8 a, bf16x8 b, f32x4 c) {
  return __builtin_amdgcn_mfma_f32_16x16x32_bf16(a, b, c, 0, 0, 0);
}

// ---------------- prep: cast x + LDS-tiled transpose/cast of weights ----------------

__global__ __launch_bounds__(256) void prep_kern(
    const float* __restrict__ x,  short* __restrict__ xb,
    const float* __restrict__ Wq, const float* __restrict__ Wk,
    const float* __restrict__ Wv, const float* __restrict__ Wp,
    short* __restrict__ WtQKV, short* __restrict__ WpT) {
  if (blockIdx.x < 3392) {
    int i = (blockIdx.x*256 + threadIdx.x)*4;
    float4 v = *(const float4*)(x + i);
    short4v r;
    r.x = f2b(v.x); r.y = f2b(v.y); r.z = f2b(v.z); r.w = f2b(v.w);
    *(short4v*)(xb + i) = r;
  } else {
    __shared__ float lds[64][65];
    const int t = blockIdx.x - 3392;      // 0..255
    const int mat = t >> 6;
    const int tt = t & 63;
    const int k0 = (tt >> 3)*64;
    const int n0 = (tt & 7)*64;
    const float* W = (mat == 0) ? Wq : (mat == 1) ? Wk : (mat == 2) ? Wv : Wp;
    const int lane6 = threadIdx.x & 63;
    const int row4  = threadIdx.x >> 6;
#pragma unroll
    for (int i = 0; i < 16; ++i) {
      int r = i*4 + row4;
      lds[r][lane6] = W[(size_t)(k0 + r)*512 + n0 + lane6];
    }
    __syncthreads();
    short* dst = (mat < 3) ? WtQKV + (size_t)mat*512*512 : WpT;
#pragma unroll
    for (int i = 0; i < 16; ++i) {
      int nr = i*4 + row4;
      dst[(size_t)(n0 + nr)*512 + k0 + lane6] = f2b(lds[lane6][nr]);
    }
  }
}

// ---------------- GEMM (r14 verbatim: BK=32, known-good) ----------------
// NOTE (r15 lesson): BK=64 + XOR-swizzled staging regressed (~2x on the GEMM
// dispatches) — do not revisit without per-dispatch counter evidence.

template<int MODE>
__global__ __launch_bounds__(256) void gemm_bt(
    const short* __restrict__ A, const short* __restrict__ Bt,
    const float* __restrict__ bias_q, const float* __restrict__ bias_k,
    const float* __restrict__ bias_v,
    short* __restrict__ Qb, short* __restrict__ Kb, short* __restrict__ Vt,
    float* __restrict__ outf) {
  __shared__ __align__(16) short At[128*32];
  __shared__ __align__(16) short Bs[128*32];
  const int tid = threadIdx.x;
  const int w = tid >> 6, lane = tid & 63;
  const int col = lane & 15, g = lane >> 4;
  const int tm = blockIdx.x, tn = blockIdx.y;
  const int wm = w >> 1, wn = w & 1;

  f32x4 acc[4][4] = {};

  for (int k0 = 0; k0 < 512; k0 += 32) {
    __syncthreads();
#pragma unroll
    for (int it = 0; it < 2; ++it) {
      int e0 = w*512 + it*2048 + lane*8;
      int row = e0 >> 5, cc = e0 & 31;
      gld16(A  + (size_t)(tm*128 + row)*512 + k0 + cc, At + w*512 + it*2048);
      gld16(Bt + (size_t)(tn*128 + row)*512 + k0 + cc, Bs + w*512 + it*2048);
    }
    __syncthreads();
    bf16x8 af[4], bfr[4];
#pragma unroll
    for (int i = 0; i < 4; ++i)
      af[i] = *(const bf16x8*)(At + (wm*64 + i*16 + col)*32 + g*8);
#pragma unroll
    for (int j = 0; j < 4; ++j)
      bfr[j] = *(const bf16x8*)(Bs + (wn*64 + j*16 + col)*32 + g*8);
#pragma unroll
    for (int i = 0; i < 4; ++i)
#pragma unroll
      for (int j = 0; j < 4; ++j)
        acc[i][j] = mfma16(af[i], bfr[j], acc[i][j]);
  }

#pragma unroll
  for (int i = 0; i < 4; ++i) {
    int mbase = tm*128 + wm*64 + i*16 + g*4;
#pragma unroll
    for (int j = 0; j < 4; ++j) {
      int ncol = tn*128 + wn*64 + j*16 + col;
#pragma unroll
      for (int r = 0; r < 4; ++r) {
        int mrow = mbase + r;
        float v = acc[i][j][r];
        if constexpr (MODE == 0) {
          float bias = (ncol < 512) ? bias_q[ncol]
                     : (ncol < 1024) ? bias_k[ncol - 512] : bias_v[ncol - 1024];
          v += bias;
          int bb = (mrow >= Ll) ? 1 : 0;
          int lpos = mrow - bb*Ll;
          int nn = ncol & 511;
          int h = nn >> 6, dd = nn & 63;
          int bh = bb*8 + h;
          if (ncol < 512) {
            // fold softmax scale (1/sqrt(64))*log2(e) into Q
            Qb[((size_t)(bh*Ll + lpos))*64 + dd] = f2b(v*0.18033688f);
          } else if (ncol < 1024) {
            Kb[((size_t)(bh*Ll + lpos))*64 + dd] = f2b(v);
          } else {
            Vt[((size_t)(bh*64 + dd))*Ll + lpos] = f2b(v);
          }
        } else {
          outf[(size_t)mrow*512 + ncol] = v + bias_q[ncol];
        }
      }
    }
  }
}

// ---------------- attention: r12/r14 structure verbatim; slots now bf16 ----------------
// NOTE (r13 lesson): no agent-scope fence/atomic fusion here — per-XCD L2s are
// non-coherent; fences force L2 writebacks that evict K/V (5x regression).
// Slot partials stored as bf16 (acc) + f32 (row-sum denominators, separate
// region) — halves fin/slot BW; error budget ~0.01 abs vs 0.067 threshold.

__global__ __launch_bounds__(256) void attn_kern(
    const short* __restrict__ Qb, const short* __restrict__ Kb,
    const short* __restrict__ Vt, short* __restrict__ slotsB,
    float* __restrict__ lsum, short* __restrict__ attout) {
  __shared__ __align__(16) short Kls[2][4096];
  __shared__ __align__(16) short Vls[2][4096];
  __shared__ __align__(16) short Pls[4][32*PST];
  const int tid = threadIdx.x;
  const int w = tid >> 6, lane = tid & 63;
  const int col = lane & 15, g = lane >> 4;

  const int v  = (blockIdx.x & 7)*150 + (blockIdx.x >> 3);  // 1200 = 8*150
  const int bh = v / UPH;
  const int lr = v - bh*UPH;

  int qsec, seg = 0, j = 0, t3 = 0;
  if (lr < 56) {
    int jj = lr/7, s = lr - jj*7;
    j = 7 - jj;
    if (s == 0)      qsec = 0;
    else if (s <= 3) { qsec = 1; seg = s - 1; }
    else             { qsec = 2; seg = s - 4; }
  } else if (lr < 72) {
    int t = lr - 56; qsec = 1 + (t & 1); j = t >> 1; seg = 3;
  } else { qsec = 3; t3 = lr - 72; }

  const int q0b = (qsec < 3) ? qsec*Tm + j*128 : MOT + ((t3 == 2) ? 192 : t3*128);
  const int t0w = j*128 + w*32;         // section-local first row of this wave
  const int q0w = q0b + w*32;

  int kbase = 0, off = 0, nb;
  bool masked;
  if (qsec == 3)      { kbase = MOT;  nb = 5;       masked = false; }
  else if (qsec == 0) { kbase = 0;    nb = 2*j + 2; masked = true; off = 0; }
  else if (seg == 0)  { kbase = 0;    nb = 2*j + 2; masked = true; off = 0; }
  else if (seg == 1)  { kbase = Tm;   nb = 2*j + 2; masked = true; off = (qsec == 1) ? 1 : 0; }
  else if (seg == 2)  { kbase = 2*Tm; nb = 2*j + 2; masked = true; off = 1; }
  else                { kbase = 0;    nb = 4;       masked = false; }  // seg3: text domains

  auto keyof = [&](int i) -> int {
    if (qsec == 3) return MOT + i*64;
    if (!masked) { int d = (i == 0) ? ((qsec == 1) ? 0 : 1) : i + 1; return MOT + d*64; }
    return kbase + i*64;
  };

  const short* Kbase_ = Kb + (size_t)bh*Ll*64;
  const short* Vbase_ = Vt + (size_t)bh*64*Ll;

  bf16x8 aq[2][2];
#pragma unroll
  for (int qf = 0; qf < 2; ++qf) {
    const short* p = Qb + ((size_t)bh*Ll + q0w + qf*16 + col)*64;
    aq[qf][0] = *(const bf16x8*)(p + g*8);
    aq[qf][1] = *(const bf16x8*)(p + 32 + g*8);
  }
  const int qv[2] = { t0w + col, t0w + 16 + col };  // per-lane q (section-local)

  float ls[2] = {0.f, 0.f};
  f32x4 out[2][4] = {};

  auto stage = [&](int buf, int key0) {
#pragma unroll
    for (int it = 0; it < 2; ++it) {
      int L = it*4096 + tid*16;
      int row = L >> 7;
      int sw = (row & 7) << 4;
      gld16((const char*)Kbase_ + (size_t)key0*128 + (L ^ sw),
            (char*)&Kls[buf][0] + it*4096 + w*1024);
      gld16((const char*)(Vbase_ + (size_t)row*Ll + key0) + ((L & 127) ^ sw),
            (char*)&Vls[buf][0] + it*4096 + w*1024);
    }
  };

  auto compute = [&](int buf, int i) {
    const int swc = (col & 7) << 4;
    f32x4 s[2][4];
    __builtin_amdgcn_s_setprio(1);
#pragma unroll
    for (int kk = 0; kk < 4; ++kk) {
      const char* base = (const char*)&Kls[buf][0] + (kk*16 + col)*128;
      bf16x8 k0 = *(const bf16x8*)(base + ((g*16) ^ swc));
      bf16x8 k1 = *(const bf16x8*)(base + ((64 + g*16) ^ swc));
#pragma unroll
      for (int qf = 0; qf < 2; ++qf) {
        f32x4 t = {0,0,0,0};
        t = mfma16(k0, aq[qf][0], t);   // swapped: S^T[key=g*4+r][q=col]
        t = mfma16(k1, aq[qf][1], t);
        s[qf][kk] = t;
      }
    }
    __builtin_amdgcn_s_setprio(0);
    const bool dm = masked && (i*64 + 63 + off > t0w);
    const int kl = i*64 + off + g*4;
    short* pw = &Pls[w][0];
#pragma unroll
    for (int qf = 0; qf < 2; ++qf) {
      float lsl = 0.f;
#pragma unroll
      for (int kk = 0; kk < 4; ++kk) {
        float pe[4];
#pragma unroll
        for (int r = 0; r < 4; ++r) {
          float p = __builtin_amdgcn_exp2f(s[qf][kk][r]);
          if (dm && (kl + kk*16 + r > qv[qf])) p = 0.f;
          pe[r] = p; lsl += p;
        }
        unsigned pk0, pk1;
        asm("v_cvt_pk_bf16_f32 %0, %1, %2" : "=v"(pk0) : "v"(pe[0]), "v"(pe[1]));
        asm("v_cvt_pk_bf16_f32 %0, %1, %2" : "=v"(pk1) : "v"(pe[2]), "v"(pe[3]));
        u32x2 pk; pk.x = pk0; pk.y = pk1;
        *(u32x2*)(pw + (qf*16 + col)*PST + kk*16 + g*4) = pk;   // 4 keys, b64
      }
      ls[qf] += lsl;
    }
    bf16x8 pa[2][2];
#pragma unroll
    for (int qf = 0; qf < 2; ++qf) {
      const short* base2 = &Pls[w][0] + (qf*16 + col)*PST;
      pa[qf][0] = *(const bf16x8*)(base2 + g*8);
      pa[qf][1] = *(const bf16x8*)(base2 + 32 + g*8);
    }
    __builtin_amdgcn_s_setprio(1);
#pragma unroll
    for (int ch = 0; ch < 4; ++ch) {
      const char* base = (const char*)&Vls[buf][0] + (ch*16 + col)*128;
      bf16x8 v0 = *(const bf16x8*)(base + ((g*16) ^ swc));
      bf16x8 v1 = *(const bf16x8*)(base + ((64 + g*16) ^ swc));
#pragma unroll
      for (int qf = 0; qf < 2; ++qf) {
        out[qf][ch] = mfma16(pa[qf][0], v0, out[qf][ch]);
        out[qf][ch] = mfma16(pa[qf][1], v1, out[qf][ch]);
      }
    }
    __builtin_amdgcn_s_setprio(0);
  };

  stage(0, keyof(0));
  for (int i = 0; i < nb; ++i) {
    if (i + 1 < nb) {
      stage((i + 1) & 1, keyof(i + 1));
      asm volatile("s_waitcnt vmcnt(4)" ::: "memory");   // tile i landed; next 4 in flight
    } else {
      asm volatile("s_waitcnt vmcnt(0)" ::: "memory");
    }
    __builtin_amdgcn_sched_barrier(0);
    __builtin_amdgcn_s_barrier();
    bool skip = masked && (t0w + 31 < i*64 + off);       // wave fully masked
    if (!skip) compute(i & 1, i);
    __builtin_amdgcn_s_barrier();                        // protect buf reuse
  }

  float rs[2];
#pragma unroll
  for (int qf = 0; qf < 2; ++qf) {
    float t = ls[qf];
    t += __shfl_xor(t, 16);
    t += __shfl_xor(t, 32);
    rs[qf] = t;                         // row-sum for q = col (section-local)
  }

  if (qsec == 1 || qsec == 2) {
    const int cidx4 = ((bh*2 + (qsec - 1))*8 + j)*4 + seg;
    short* sp = slotsB + (size_t)cidx4*8192;
#pragma unroll
    for (int qf = 0; qf < 2; ++qf) {
#pragma unroll
      for (int ch = 0; ch < 4; ++ch)
#pragma unroll
        for (int r = 0; r < 4; ++r)
          sp[(w*32 + qf*16 + g*4 + r)*64 + ch*16 + col] = f2b(out[qf][ch][r]);
      if (g == 0)
        lsum[(size_t)cidx4*128 + w*32 + qf*16 + col] = rs[qf];
    }
  } else {
    const int b = bh >> 3, h = bh & 7;
#pragma unroll
    for (int qf = 0; qf < 2; ++qf)
#pragma unroll
      for (int r = 0; r < 4; ++r) {
        float dv = __shfl(rs[qf], g*4 + r);   // gather row-indexed sum
        float inv = 1.0f / dv;
        size_t rowoff = ((size_t)(b*Ll + q0w + qf*16 + g*4 + r))*512 + h*64;
#pragma unroll
        for (int ch = 0; ch < 4; ++ch)
          attout[rowoff + ch*16 + col] = f2b(out[qf][ch][r]*inv);
      }
  }
}

// finalize: sum 4 bf16 seg-slots (+f32 denominators) per sec1/2 row, write att
__global__ __launch_bounds__(256) void fin_kern(const short* __restrict__ slotsB,
                                                const float* __restrict__ lsum,
                                                short* __restrict__ attout) {
  const int w = threadIdx.x >> 6, lane = threadIdx.x & 63;
  const int ridx = blockIdx.x*4 + w;       // 0..32767
  const int bh = ridx >> 11;
  const int rr = ridx & 2047;
  const int qsec = 1 + (rr >> 10);
  const int rl = rr & 1023;
  const int j = rl >> 7;
  const int row_local = rl & 127;
  const int grp = (bh*2 + (qsec - 1))*8 + j;
  const short* base = slotsB + (size_t)grp*4*8192;
  const float* lb = lsum + (size_t)grp*4*128;
  float a = 0.f, l = 0.f;
#pragma unroll
  for (int s = 0; s < 4; ++s) {
    a += b2f(base[s*8192 + row_local*64 + lane]);
    l += lb[s*128 + row_local];
  }
  const int b = bh >> 3, h = bh & 7;
  attout[((size_t)(b*Ll + qsec*Tm + rl))*512 + h*64 + lane] = f2b(a / l);
}

// ---------------- launch ----------------

extern "C" void kernel_launch(void* const* d_in, const int* in_sizes, int n_in,
                              void* d_out, int out_size, void* d_ws, size_t ws_size,
                              hipStream_t stream) {
  const float* x  = (const float*)d_in[0];
  const float* Wq = (const float*)d_in[1];
  const float* bq = (const float*)d_in[2];
  const float* Wk = (const float*)d_in[3];
  const float* bk = (const float*)d_in[4];
  const float* Wv = (const float*)d_in[5];
  const float* bv = (const float*)d_in[6];
  const float* Wp = (const float*)d_in[7];
  const float* bp = (const float*)d_in[8];
  float* out = (float*)d_out;

  short* ws = (short*)d_ws;
  constexpr size_t SZ  = (size_t)Mm*512;
  short* xb    = ws;
  short* WtQKV = xb + SZ;
  short* WpT   = WtQKV + (size_t)1536*512;
  short* Qb    = WpT + (size_t)512*512;
  short* Kb    = Qb + SZ;
  short* Vt    = Kb + SZ;
  short* att   = Vt + SZ;
  short* slotsB = att + SZ;                         // 256*4*8192 bf16 = 16.8 MB
  float* lsum  = (float*)(slotsB + (size_t)256*4*8192);  // 256*4*128 f32 = 512 KB

  prep_kern<<<dim3(3392 + 256), dim3(256), 0, stream>>>(x, xb, Wq, Wk, Wv, Wp,
                                                        WtQKV, WpT);
  gemm_bt<0><<<dim3(53, 12), dim3(256), 0, stream>>>(xb, WtQKV, bq, bk, bv,
                                                     Qb, Kb, Vt, nullptr);
  attn_kern<<<dim3(1200), dim3(256), 0, stream>>>(Qb, Kb, Vt, slotsB, lsum, att);
  fin_kern<<<dim3(8192), dim3(256), 0, stream>>>(slotsB, lsum, att);
  gemm_bt<1><<<dim3(53, 4), dim3(256), 0, stream>>>(att, WpT, bp, nullptr, nullptr,
                                                    nullptr, nullptr, nullptr, out);
}

// Round 18
// 90.695 us; speedup vs baseline: 1.1214x; 1.0049x over previous
//
#include <hip/hip_runtime.h>
#include <hip/hip_bf16.h>
#include <math.h>

typedef __attribute__((ext_vector_type(8))) short bf16x8;
typedef __attribute__((ext_vector_type(4))) short short4v;
typedef __attribute__((ext_vector_type(4))) float f32x4;
typedef __attribute__((ext_vector_type(2))) unsigned int u32x2;

#define DEVI __device__ __forceinline__

constexpr int Bb  = 2;
constexpr int Tm  = 1024;
constexpr int Ntx = 64;
constexpr int Hh  = 8;
constexpr int Ll  = 3*Tm + 5*Ntx;   // 3392
constexpr int Mm  = Bb*Ll;          // 6784
constexpr int MOT = 3*Tm;           // 3072
constexpr int UPH = 75;             // units per (b,h)
constexpr int PST = 72;             // P LDS stride (shorts)

DEVI short f2b(float f) {
  unsigned u = __builtin_bit_cast(unsigned, f);
  u = u + 0x7fffu + ((u >> 16) & 1u);
  return (short)(u >> 16);
}

DEVI float b2f(short s) {
  unsigned u = ((unsigned)(unsigned short)s) << 16;
  return __builtin_bit_cast(float, u);
}

DEVI void gld16(const void* g, void* l) {
  __builtin_amdgcn_global_load_lds(
      (const __attribute__((address_space(1))) unsigned*)g,
      (__attribute__((address_space(3))) unsigned*)l, 16, 0, 0);
}

DEVI f32x4 mfma16(bf16x8 a, bf16x8 b, f32x4 c) {
  return __builtin_amdgcn_mfma_f32_16x16x32_bf16(a, b, c, 0, 0, 0);
}

// ---------------- prep: cast x + LDS-tiled transpose/cast of weights ----------------

__global__ __launch_bounds__(256) void prep_kern(
    const float* __restrict__ x,  short* __restrict__ xb,
    const float* __restrict__ Wq, const float* __restrict__ Wk,
    const float* __restrict__ Wv, const float* __restrict__ Wp,
    short* __restrict__ WtQKV, short* __restrict__ WpT) {
  if (blockIdx.x < 3392) {
    int i = (blockIdx.x*256 + threadIdx.x)*4;
    float4 v = *(const float4*)(x + i);
    short4v r;
    r.x = f2b(v.x); r.y = f2b(v.y); r.z = f2b(v.z); r.w = f2b(v.w);
    *(short4v*)(xb + i) = r;
  } else {
    __shared__ float lds[64][65];
    const int t = blockIdx.x - 3392;      // 0..255
    const int mat = t >> 6;
    const int tt = t & 63;
    const int k0 = (tt >> 3)*64;
    const int n0 = (tt & 7)*64;
    const float* W = (mat == 0) ? Wq : (mat == 1) ? Wk : (mat == 2) ? Wv : Wp;
    const int lane6 = threadIdx.x & 63;
    const int row4  = threadIdx.x >> 6;
#pragma unroll
    for (int i = 0; i < 16; ++i) {
      int r = i*4 + row4;
      lds[r][lane6] = W[(size_t)(k0 + r)*512 + n0 + lane6];
    }
    __syncthreads();
    short* dst = (mat < 3) ? WtQKV + (size_t)mat*512*512 : WpT;
#pragma unroll
    for (int i = 0; i < 16; ++i) {
      int nr = i*4 + row4;
      dst[(size_t)(n0 + nr)*512 + k0 + lane6] = f2b(lds[lane6][nr]);
    }
  }
}

// ---------------- GEMM: 64x128 tiles (grid-starvation fix; BK=32 structure kept) ----------------
// r15 lesson: BK/swizzle changes regress. This changes ONLY the M-tile (128->64)
// to double blocks: gemm1 212->424 blocks (0.83->1.7/CU), gemm0 636->1272 (5/CU).
// Wave w owns 64x32 quadrant (acc[4][2]); A-stage 1 gld16/thread, B-stage 2.

template<int MODE>
__global__ __launch_bounds__(256) void gemm_bt(
    const short* __restrict__ A, const short* __restrict__ Bt,
    const float* __restrict__ bias_q, const float* __restrict__ bias_k,
    const float* __restrict__ bias_v,
    short* __restrict__ Qb, short* __restrict__ Kb, short* __restrict__ Vt,
    float* __restrict__ outf) {
  __shared__ __align__(16) short At[64*32];    // 4KB
  __shared__ __align__(16) short Bs[128*32];   // 8KB
  const int tid = threadIdx.x;
  const int w = tid >> 6, lane = tid & 63;
  const int col = lane & 15, g = lane >> 4;
  const int tm = blockIdx.x, tn = blockIdx.y;

  f32x4 acc[4][2] = {};

  for (int k0 = 0; k0 < 512; k0 += 32) {
    __syncthreads();
    {
      // A: 64 rows x 32 cols = 2048 elems, 1 gld16/thread
      int e0 = tid*8;
      int row = e0 >> 5, cc = e0 & 31;
      gld16(A + (size_t)(tm*64 + row)*512 + k0 + cc, (char*)At + w*1024);
#pragma unroll
      for (int it = 0; it < 2; ++it) {
        int e1 = w*512 + it*2048 + lane*8;
        int brow = e1 >> 5, bcc = e1 & 31;
        gld16(Bt + (size_t)(tn*128 + brow)*512 + k0 + bcc,
              (char*)Bs + it*4096 + w*1024);
      }
    }
    __syncthreads();
    bf16x8 af[4], bfr[2];
#pragma unroll
    for (int i = 0; i < 4; ++i)
      af[i] = *(const bf16x8*)(At + (i*16 + col)*32 + g*8);
#pragma unroll
    for (int j = 0; j < 2; ++j)
      bfr[j] = *(const bf16x8*)(Bs + (w*32 + j*16 + col)*32 + g*8);
#pragma unroll
    for (int i = 0; i < 4; ++i)
#pragma unroll
      for (int j = 0; j < 2; ++j)
        acc[i][j] = mfma16(af[i], bfr[j], acc[i][j]);
  }

#pragma unroll
  for (int i = 0; i < 4; ++i) {
    int mbase = tm*64 + i*16 + g*4;
#pragma unroll
    for (int j = 0; j < 2; ++j) {
      int ncol = tn*128 + w*32 + j*16 + col;
#pragma unroll
      for (int r = 0; r < 4; ++r) {
        int mrow = mbase + r;
        float v = acc[i][j][r];
        if constexpr (MODE == 0) {
          float bias = (ncol < 512) ? bias_q[ncol]
                     : (ncol < 1024) ? bias_k[ncol - 512] : bias_v[ncol - 1024];
          v += bias;
          int bb = (mrow >= Ll) ? 1 : 0;
          int lpos = mrow - bb*Ll;
          int nn = ncol & 511;
          int h = nn >> 6, dd = nn & 63;
          int bh = bb*8 + h;
          if (ncol < 512) {
            // fold softmax scale (1/sqrt(64))*log2(e) into Q
            Qb[((size_t)(bh*Ll + lpos))*64 + dd] = f2b(v*0.18033688f);
          } else if (ncol < 1024) {
            Kb[((size_t)(bh*Ll + lpos))*64 + dd] = f2b(v);
          } else {
            Vt[((size_t)(bh*64 + dd))*Ll + lpos] = f2b(v);
          }
        } else {
          outf[(size_t)mrow*512 + ncol] = v + bias_q[ncol];
        }
      }
    }
  }
}

// ---------------- attention: r12/r14 structure verbatim; bf16 slots (r17) ----------------
// NOTE (r13 lesson): no agent-scope fence/atomic fusion here — per-XCD L2s are
// non-coherent; fences force L2 writebacks that evict K/V (5x regression).

__global__ __launch_bounds__(256) void attn_kern(
    const short* __restrict__ Qb, const short* __restrict__ Kb,
    const short* __restrict__ Vt, short* __restrict__ slotsB,
    float* __restrict__ lsum, short* __restrict__ attout) {
  __shared__ __align__(16) short Kls[2][4096];
  __shared__ __align__(16) short Vls[2][4096];
  __shared__ __align__(16) short Pls[4][32*PST];
  const int tid = threadIdx.x;
  const int w = tid >> 6, lane = tid & 63;
  const int col = lane & 15, g = lane >> 4;

  const int v  = (blockIdx.x & 7)*150 + (blockIdx.x >> 3);  // 1200 = 8*150
  const int bh = v / UPH;
  const int lr = v - bh*UPH;

  int qsec, seg = 0, j = 0, t3 = 0;
  if (lr < 56) {
    int jj = lr/7, s = lr - jj*7;
    j = 7 - jj;
    if (s == 0)      qsec = 0;
    else if (s <= 3) { qsec = 1; seg = s - 1; }
    else             { qsec = 2; seg = s - 4; }
  } else if (lr < 72) {
    int t = lr - 56; qsec = 1 + (t & 1); j = t >> 1; seg = 3;
  } else { qsec = 3; t3 = lr - 72; }

  const int q0b = (qsec < 3) ? qsec*Tm + j*128 : MOT + ((t3 == 2) ? 192 : t3*128);
  const int t0w = j*128 + w*32;         // section-local first row of this wave
  const int q0w = q0b + w*32;

  int kbase = 0, off = 0, nb;
  bool masked;
  if (qsec == 3)      { kbase = MOT;  nb = 5;       masked = false; }
  else if (qsec == 0) { kbase = 0;    nb = 2*j + 2; masked = true; off = 0; }
  else if (seg == 0)  { kbase = 0;    nb = 2*j + 2; masked = true; off = 0; }
  else if (seg == 1)  { kbase = Tm;   nb = 2*j + 2; masked = true; off = (qsec == 1) ? 1 : 0; }
  else if (seg == 2)  { kbase = 2*Tm; nb = 2*j + 2; masked = true; off = 1; }
  else                { kbase = 0;    nb = 4;       masked = false; }  // seg3: text domains

  auto keyof = [&](int i) -> int {
    if (qsec == 3) return MOT + i*64;
    if (!masked) { int d = (i == 0) ? ((qsec == 1) ? 0 : 1) : i + 1; return MOT + d*64; }
    return kbase + i*64;
  };

  const short* Kbase_ = Kb + (size_t)bh*Ll*64;
  const short* Vbase_ = Vt + (size_t)bh*64*Ll;

  bf16x8 aq[2][2];
#pragma unroll
  for (int qf = 0; qf < 2; ++qf) {
    const short* p = Qb + ((size_t)bh*Ll + q0w + qf*16 + col)*64;
    aq[qf][0] = *(const bf16x8*)(p + g*8);
    aq[qf][1] = *(const bf16x8*)(p + 32 + g*8);
  }
  const int qv[2] = { t0w + col, t0w + 16 + col };  // per-lane q (section-local)

  float ls[2] = {0.f, 0.f};
  f32x4 out[2][4] = {};

  auto stage = [&](int buf, int key0) {
#pragma unroll
    for (int it = 0; it < 2; ++it) {
      int L = it*4096 + tid*16;
      int row = L >> 7;
      int sw = (row & 7) << 4;
      gld16((const char*)Kbase_ + (size_t)key0*128 + (L ^ sw),
            (char*)&Kls[buf][0] + it*4096 + w*1024);
      gld16((const char*)(Vbase_ + (size_t)row*Ll + key0) + ((L & 127) ^ sw),
            (char*)&Vls[buf][0] + it*4096 + w*1024);
    }
  };

  auto compute = [&](int buf, int i) {
    const int swc = (col & 7) << 4;
    f32x4 s[2][4];
    __builtin_amdgcn_s_setprio(1);
#pragma unroll
    for (int kk = 0; kk < 4; ++kk) {
      const char* base = (const char*)&Kls[buf][0] + (kk*16 + col)*128;
      bf16x8 k0 = *(const bf16x8*)(base + ((g*16) ^ swc));
      bf16x8 k1 = *(const bf16x8*)(base + ((64 + g*16) ^ swc));
#pragma unroll
      for (int qf = 0; qf < 2; ++qf) {
        f32x4 t = {0,0,0,0};
        t = mfma16(k0, aq[qf][0], t);   // swapped: S^T[key=g*4+r][q=col]
        t = mfma16(k1, aq[qf][1], t);
        s[qf][kk] = t;
      }
    }
    __builtin_amdgcn_s_setprio(0);
    const bool dm = masked && (i*64 + 63 + off > t0w);
    const int kl = i*64 + off + g*4;
    short* pw = &Pls[w][0];
#pragma unroll
    for (int qf = 0; qf < 2; ++qf) {
      float lsl = 0.f;
#pragma unroll
      for (int kk = 0; kk < 4; ++kk) {
        float pe[4];
#pragma unroll
        for (int r = 0; r < 4; ++r) {
          float p = __builtin_amdgcn_exp2f(s[qf][kk][r]);
          if (dm && (kl + kk*16 + r > qv[qf])) p = 0.f;
          pe[r] = p; lsl += p;
        }
        unsigned pk0, pk1;
        asm("v_cvt_pk_bf16_f32 %0, %1, %2" : "=v"(pk0) : "v"(pe[0]), "v"(pe[1]));
        asm("v_cvt_pk_bf16_f32 %0, %1, %2" : "=v"(pk1) : "v"(pe[2]), "v"(pe[3]));
        u32x2 pk; pk.x = pk0; pk.y = pk1;
        *(u32x2*)(pw + (qf*16 + col)*PST + kk*16 + g*4) = pk;   // 4 keys, b64
      }
      ls[qf] += lsl;
    }
    bf16x8 pa[2][2];
#pragma unroll
    for (int qf = 0; qf < 2; ++qf) {
      const short* base2 = &Pls[w][0] + (qf*16 + col)*PST;
      pa[qf][0] = *(const bf16x8*)(base2 + g*8);
      pa[qf][1] = *(const bf16x8*)(base2 + 32 + g*8);
    }
    __builtin_amdgcn_s_setprio(1);
#pragma unroll
    for (int ch = 0; ch < 4; ++ch) {
      const char* base = (const char*)&Vls[buf][0] + (ch*16 + col)*128;
      bf16x8 v0 = *(const bf16x8*)(base + ((g*16) ^ swc));
      bf16x8 v1 = *(const bf16x8*)(base + ((64 + g*16) ^ swc));
#pragma unroll
      for (int qf = 0; qf < 2; ++qf) {
        out[qf][ch] = mfma16(pa[qf][0], v0, out[qf][ch]);
        out[qf][ch] = mfma16(pa[qf][1], v1, out[qf][ch]);
      }
    }
    __builtin_amdgcn_s_setprio(0);
  };

  stage(0, keyof(0));
  for (int i = 0; i < nb; ++i) {
    if (i + 1 < nb) {
      stage((i + 1) & 1, keyof(i + 1));
      asm volatile("s_waitcnt vmcnt(4)" ::: "memory");   // tile i landed; next 4 in flight
    } else {
      asm volatile("s_waitcnt vmcnt(0)" ::: "memory");
    }
    __builtin_amdgcn_sched_barrier(0);
    __builtin_amdgcn_s_barrier();
    bool skip = masked && (t0w + 31 < i*64 + off);       // wave fully masked
    if (!skip) compute(i & 1, i);
    __builtin_amdgcn_s_barrier();                        // protect buf reuse
  }

  float rs[2];
#pragma unroll
  for (int qf = 0; qf < 2; ++qf) {
    float t = ls[qf];
    t += __shfl_xor(t, 16);
    t += __shfl_xor(t, 32);
    rs[qf] = t;                         // row-sum for q = col (section-local)
  }

  if (qsec == 1 || qsec == 2) {
    const int cidx4 = ((bh*2 + (qsec - 1))*8 + j)*4 + seg;
    short* sp = slotsB + (size_t)cidx4*8192;
#pragma unroll
    for (int qf = 0; qf < 2; ++qf) {
#pragma unroll
      for (int ch = 0; ch < 4; ++ch)
#pragma unroll
        for (int r = 0; r < 4; ++r)
          sp[(w*32 + qf*16 + g*4 + r)*64 + ch*16 + col] = f2b(out[qf][ch][r]);
      if (g == 0)
        lsum[(size_t)cidx4*128 + w*32 + qf*16 + col] = rs[qf];
    }
  } else {
    const int b = bh >> 3, h = bh & 7;
#pragma unroll
    for (int qf = 0; qf < 2; ++qf)
#pragma unroll
      for (int r = 0; r < 4; ++r) {
        float dv = __shfl(rs[qf], g*4 + r);   // gather row-indexed sum
        float inv = 1.0f / dv;
        size_t rowoff = ((size_t)(b*Ll + q0w + qf*16 + g*4 + r))*512 + h*64;
#pragma unroll
        for (int ch = 0; ch < 4; ++ch)
          attout[rowoff + ch*16 + col] = f2b(out[qf][ch][r]*inv);
      }
  }
}

// finalize: sum 4 bf16 seg-slots (+f32 denominators) per sec1/2 row, write att
__global__ __launch_bounds__(256) void fin_kern(const short* __restrict__ slotsB,
                                                const float* __restrict__ lsum,
                                                short* __restrict__ attout) {
  const int w = threadIdx.x >> 6, lane = threadIdx.x & 63;
  const int ridx = blockIdx.x*4 + w;       // 0..32767
  const int bh = ridx >> 11;
  const int rr = ridx & 2047;
  const int qsec = 1 + (rr >> 10);
  const int rl = rr & 1023;
  const int j = rl >> 7;
  const int row_local = rl & 127;
  const int grp = (bh*2 + (qsec - 1))*8 + j;
  const short* base = slotsB + (size_t)grp*4*8192;
  const float* lb = lsum + (size_t)grp*4*128;
  float a = 0.f, l = 0.f;
#pragma unroll
  for (int s = 0; s < 4; ++s) {
    a += b2f(base[s*8192 + row_local*64 + lane]);
    l += lb[s*128 + row_local];
  }
  const int b = bh >> 3, h = bh & 7;
  attout[((size_t)(b*Ll + qsec*Tm + rl))*512 + h*64 + lane] = f2b(a / l);
}

// ---------------- launch ----------------

extern "C" void kernel_launch(void* const* d_in, const int* in_sizes, int n_in,
                              void* d_out, int out_size, void* d_ws, size_t ws_size,
                              hipStream_t stream) {
  const float* x  = (const float*)d_in[0];
  const float* Wq = (const float*)d_in[1];
  const float* bq = (const float*)d_in[2];
  const float* Wk = (const float*)d_in[3];
  const float* bk = (const float*)d_in[4];
  const float* Wv = (const float*)d_in[5];
  const float* bv = (const float*)d_in[6];
  const float* Wp = (const float*)d_in[7];
  const float* bp = (const float*)d_in[8];
  float* out = (float*)d_out;

  short* ws = (short*)d_ws;
  constexpr size_t SZ  = (size_t)Mm*512;
  short* xb    = ws;
  short* WtQKV = xb + SZ;
  short* WpT   = WtQKV + (size_t)1536*512;
  short* Qb    = WpT + (size_t)512*512;
  short* Kb    = Qb + SZ;
  short* Vt    = Kb + SZ;
  short* att   = Vt + SZ;
  short* slotsB = att + SZ;                         // 256*4*8192 bf16 = 16.8 MB
  float* lsum  = (float*)(slotsB + (size_t)256*4*8192);  // 256*4*128 f32 = 512 KB

  prep_kern<<<dim3(3392 + 256), dim3(256), 0, stream>>>(x, xb, Wq, Wk, Wv, Wp,
                                                        WtQKV, WpT);
  gemm_bt<0><<<dim3(106, 12), dim3(256), 0, stream>>>(xb, WtQKV, bq, bk, bv,
                                                      Qb, Kb, Vt, nullptr);
  attn_kern<<<dim3(1200), dim3(256), 0, stream>>>(Qb, Kb, Vt, slotsB, lsum, att);
  fin_kern<<<dim3(8192), dim3(256), 0, stream>>>(slotsB, lsum, att);
  gemm_bt<1><<<dim3(106, 4), dim3(256), 0, stream>>>(att, WpT, bp, nullptr, nullptr,
                                                     nullptr, nullptr, nullptr, out);
}